// Round 4
// baseline (143.155 us; speedup 1.0000x reference)
//
#include <hip/hip_runtime.h>
#include <hip/hip_bf16.h>

#define N_V   20000
#define KNB   16
#define DCODE 256
#define H1    512
#define H2    1024
#define M3    60000   // N_V * 3

// ws layout (float offsets)
#define OFF_V     0          // 60000
#define OFF_GV    60000      // 60000 -> 120000
#define OFF_GZ2   120000     // 1024  -> 121024
#define OFF_GZ1   121024     // 512   -> 121536
#define OFF_H1    121536     // 512   -> 122048
#define OFF_H2    122048     // 1024  -> 123072
#define OFF_E     123072     // double (2 float slots; byte 492288 % 8 == 0)

// ---------------- fused MLP head: z1/h1 (redundant per block), z2/h2 slice ----------------
// grid 32, block 256. Also inits v = b3, gv = 0, E = 0.
__global__ void k_mlp(const float* __restrict__ code, const float* __restrict__ W1,
                      const float* __restrict__ b1, const float* __restrict__ W2,
                      const float* __restrict__ b2, const float* __restrict__ b3,
                      float* __restrict__ ws) {
    __shared__ float h1s[H1];
    __shared__ float zp[8][32];
    int t = threadIdx.x;

    // full z1 -> h1 (every block computes it; W1 is L2-resident after first touch)
    for (int mm = t; mm < H1; mm += 256) {
        float acc = 0.f;
#pragma unroll 4
        for (int d = 0; d < DCODE; ++d)
            acc += code[d] * W1[(size_t)d * H1 + mm];
        h1s[mm] = fmaxf(acc + b1[mm], 0.f);
    }
    __syncthreads();
    if (blockIdx.x == 0)
        for (int mm = t; mm < H1; mm += 256) ws[OFF_H1 + mm] = h1s[mm];

    // z2 slice: 32 columns per block, d split 8 ways
    int g = t >> 5, mm = t & 31;
    int m = blockIdx.x * 32 + mm;
    float acc = 0.f;
    int d0 = g * 64;
#pragma unroll 8
    for (int d = d0; d < d0 + 64; ++d)
        acc += h1s[d] * W2[(size_t)d * H2 + m];
    zp[g][mm] = acc;
    __syncthreads();
    if (g == 0) {
        float s = b2[m];
#pragma unroll
        for (int p = 0; p < 8; ++p) s += zp[p][mm];
        ws[OFF_H2 + m] = fmaxf(s, 0.f);
    }

    // init v = b3, gv = 0, E = 0
    int gid = blockIdx.x * 256 + t;                 // 8192 threads
    for (int idx = gid; idx < M3; idx += 8192) {
        ws[OFF_V + idx]  = b3[idx];
        ws[OFF_GV + idx] = 0.f;
    }
    if (gid == 0) { ws[OFF_E] = 0.f; ws[OFF_E + 1] = 0.f; }
}

// ---------------- W3 forward: v += sum_j h2[j] W3[j,:] over live rows ----------------
// grid (59, 8), block 256: per-block compaction of its 128-row chunk, atomic v add
__global__ void k_l3v(const float* __restrict__ W3, float* __restrict__ ws) {
    __shared__ float rh[128];
    __shared__ int   rlist[128];
    __shared__ int   scan[128];
    int t = threadIdx.x;
    int rbase = blockIdx.y * 128;

    float hv = 0.f; int flag = 0;
    if (t < 128) {
        hv = ws[OFF_H2 + rbase + t];
        flag = (hv > 0.f) ? 1 : 0;
        scan[t] = flag;
    }
    __syncthreads();
    for (int off = 1; off < 128; off <<= 1) {
        int x = 0;
        if (t < 128 && t >= off) x = scan[t - off];
        __syncthreads();
        if (t < 128) scan[t] += x;
        __syncthreads();
    }
    if (t < 128 && flag) {
        int idx = scan[t] - 1;
        rlist[idx] = rbase + t;
        rh[idx] = hv;
    }
    __syncthreads();
    int n = scan[127];

    int m4 = blockIdx.x * 1024 + t * 4;
    if (m4 >= M3) return;
    float ax = 0.f, ay = 0.f, az = 0.f, aw = 0.f;
    int ii = 0;
    for (; ii + 3 < n; ii += 4) {
        int r0 = rlist[ii], r1 = rlist[ii + 1], r2 = rlist[ii + 2], r3 = rlist[ii + 3];
        float h0 = rh[ii], h1v = rh[ii + 1], h2v = rh[ii + 2], h3 = rh[ii + 3];
        float4 w0 = *reinterpret_cast<const float4*>(&W3[(size_t)r0 * M3 + m4]);
        float4 w1 = *reinterpret_cast<const float4*>(&W3[(size_t)r1 * M3 + m4]);
        float4 w2 = *reinterpret_cast<const float4*>(&W3[(size_t)r2 * M3 + m4]);
        float4 w3 = *reinterpret_cast<const float4*>(&W3[(size_t)r3 * M3 + m4]);
        ax += h0 * w0.x + h1v * w1.x + h2v * w2.x + h3 * w3.x;
        ay += h0 * w0.y + h1v * w1.y + h2v * w2.y + h3 * w3.y;
        az += h0 * w0.z + h1v * w1.z + h2v * w2.z + h3 * w3.z;
        aw += h0 * w0.w + h1v * w1.w + h2v * w2.w + h3 * w3.w;
    }
    for (; ii < n; ++ii) {
        int r0 = rlist[ii]; float h0 = rh[ii];
        float4 w0 = *reinterpret_cast<const float4*>(&W3[(size_t)r0 * M3 + m4]);
        ax += h0 * w0.x; ay += h0 * w0.y; az += h0 * w0.z; aw += h0 * w0.w;
    }
    atomicAdd(&ws[OFF_V + m4 + 0], ax);
    atomicAdd(&ws[OFF_V + m4 + 1], ay);
    atomicAdd(&ws[OFF_V + m4 + 2], az);
    atomicAdd(&ws[OFF_V + m4 + 3], aw);
}

// ---------------- ARAP fused (fp32): rotation fit + residual + energy + gradient ----------------

__device__ inline void jrotf(float a[3][3], float v[3][3], int p, int q) {
    float apq = a[p][q];
    if (fabsf(apq) < 1e-30f) return;
    float theta = (a[q][q] - a[p][p]) / (2.0f * apq);
    float t;
    if (fabsf(theta) > 1e18f) t = 0.5f / theta;
    else t = copysignf(1.0f, theta) / (fabsf(theta) + sqrtf(theta * theta + 1.0f));
    float c = 1.0f / sqrtf(t * t + 1.0f);
    float s = t * c;
    float app = a[p][p], aqq = a[q][q];
    a[p][p] = app - t * apq;
    a[q][q] = aqq + t * apq;
    a[p][q] = 0.0f; a[q][p] = 0.0f;
    int r = 3 - p - q;
    float arp = a[r][p], arq = a[r][q];
    a[r][p] = c * arp - s * arq; a[p][r] = a[r][p];
    a[r][q] = s * arp + c * arq; a[q][r] = a[r][q];
#pragma unroll
    for (int k2 = 0; k2 < 3; ++k2) {
        float vkp = v[k2][p], vkq = v[k2][q];
        v[k2][p] = c * vkp - s * vkq;
        v[k2][q] = s * vkp + c * vkq;
    }
}

__device__ void compute_Rf(const float S[3][3], float R[3][3]) {
    float A[3][3], V[3][3];
#pragma unroll
    for (int a = 0; a < 3; ++a)
#pragma unroll
        for (int b = 0; b < 3; ++b) {
            float s = 0.0f;
#pragma unroll
            for (int c = 0; c < 3; ++c) s += S[c][a] * S[c][b];
            A[a][b] = s;
            V[a][b] = (a == b) ? 1.0f : 0.0f;
        }
    for (int sweep = 0; sweep < 15; ++sweep) {
        float off = A[0][1]*A[0][1] + A[0][2]*A[0][2] + A[1][2]*A[1][2];
        float dg  = A[0][0]*A[0][0] + A[1][1]*A[1][1] + A[2][2]*A[2][2];
        if (off <= 1e-12f * (dg + 1e-30f)) break;
        jrotf(A, V, 0, 1); jrotf(A, V, 0, 2); jrotf(A, V, 1, 2);
    }
    int id[3] = {0, 1, 2};
    if (A[id[0]][id[0]] < A[id[1]][id[1]]) { int t = id[0]; id[0] = id[1]; id[1] = t; }
    if (A[id[0]][id[0]] < A[id[2]][id[2]]) { int t = id[0]; id[0] = id[2]; id[2] = t; }
    if (A[id[1]][id[1]] < A[id[2]][id[2]]) { int t = id[1]; id[1] = id[2]; id[2] = t; }
    float v0[3], v1[3], v2[3];
#pragma unroll
    for (int r = 0; r < 3; ++r) {
        v0[r] = V[r][id[0]]; v1[r] = V[r][id[1]]; v2[r] = V[r][id[2]];
    }
    float u0[3], u1[3], u2[3];
#pragma unroll
    for (int a = 0; a < 3; ++a)
        u0[a] = S[a][0]*v0[0] + S[a][1]*v0[1] + S[a][2]*v0[2];
    float n0 = sqrtf(u0[0]*u0[0] + u0[1]*u0[1] + u0[2]*u0[2]);
    if (!(n0 > 1e-20f)) {
#pragma unroll
        for (int a = 0; a < 3; ++a)
#pragma unroll
            for (int c = 0; c < 3; ++c) R[a][c] = (a == c) ? 1.0f : 0.0f;
        return;
    }
#pragma unroll
    for (int a = 0; a < 3; ++a) u0[a] /= n0;
    float t1[3];
#pragma unroll
    for (int a = 0; a < 3; ++a)
        t1[a] = S[a][0]*v1[0] + S[a][1]*v1[1] + S[a][2]*v1[2];
    float dp = u0[0]*t1[0] + u0[1]*t1[1] + u0[2]*t1[2];
#pragma unroll
    for (int a = 0; a < 3; ++a) t1[a] -= dp * u0[a];
    float n1 = sqrtf(t1[0]*t1[0] + t1[1]*t1[1] + t1[2]*t1[2]);
    if (n1 > 1e-5f * n0) {
#pragma unroll
        for (int a = 0; a < 3; ++a) u1[a] = t1[a] / n1;
    } else {
        int m = (fabsf(u0[0]) <= fabsf(u0[1]) && fabsf(u0[0]) <= fabsf(u0[2])) ? 0
              : (fabsf(u0[1]) <= fabsf(u0[2]) ? 1 : 2);
        float e[3] = {0.0f, 0.0f, 0.0f}; e[m] = 1.0f;
        float cx[3] = { u0[1]*e[2] - u0[2]*e[1],
                        u0[2]*e[0] - u0[0]*e[2],
                        u0[0]*e[1] - u0[1]*e[0] };
        float nn = sqrtf(cx[0]*cx[0] + cx[1]*cx[1] + cx[2]*cx[2]);
#pragma unroll
        for (int a = 0; a < 3; ++a) u1[a] = cx[a] / nn;
    }
    u2[0] = u0[1]*u1[2] - u0[2]*u1[1];
    u2[1] = u0[2]*u1[0] - u0[0]*u1[2];
    u2[2] = u0[0]*u1[1] - u0[1]*u1[0];
    float d = v0[0]*(v1[1]*v2[2] - v1[2]*v2[1])
            - v0[1]*(v1[0]*v2[2] - v1[2]*v2[0])
            + v0[2]*(v1[0]*v2[1] - v1[1]*v2[0]);
#pragma unroll
    for (int a = 0; a < 3; ++a)
#pragma unroll
        for (int c = 0; c < 3; ++c)
            R[a][c] = v0[a]*u0[c] + v1[a]*u1[c] + d * (v2[a]*u2[c]);
}

// grid 313, block 64 (1 wave)
__global__ void k_arap(const float* __restrict__ xyz1, const float* __restrict__ wmat,
                       const int* __restrict__ nbr, const int* __restrict__ nnum,
                       float* __restrict__ ws) {
    const float* recon = ws + OFF_V;
    float* gv = ws + OFF_GV;
    int i = blockIdx.x * 64 + threadIdx.x;
    double pv = 0.0;
    if (i < N_V) {
        int num = nnum[i]; if (num > KNB) num = KNB;
        float cr0 = xyz1[3*i], cr1 = xyz1[3*i+1], cr2 = xyz1[3*i+2];
        float cd0 = recon[3*i], cd1 = recon[3*i+1], cd2 = recon[3*i+2];
        float S[3][3] = {{0,0,0},{0,0,0},{0,0,0}};
        for (int k = 0; k < num; ++k) {
            int j = nbr[i*KNB + k];
            float w = wmat[i*KNB + k];
            float er0 = xyz1[3*j]  - cr0, er1 = xyz1[3*j+1] - cr1, er2 = xyz1[3*j+2] - cr2;
            float ed0 = recon[3*j] - cd0, ed1 = recon[3*j+1] - cd1, ed2 = recon[3*j+2] - cd2;
            S[0][0] += w*er0*ed0; S[0][1] += w*er0*ed1; S[0][2] += w*er0*ed2;
            S[1][0] += w*er1*ed0; S[1][1] += w*er1*ed1; S[1][2] += w*er1*ed2;
            S[2][0] += w*er2*ed0; S[2][1] += w*er2*ed1; S[2][2] += w*er2*ed2;
        }
        float R[3][3];
        compute_Rf(S, R);
        const float gscale = 2.0f / (float)N_V;
        float own0 = 0.f, own1 = 0.f, own2 = 0.f;
        for (int k = 0; k < num; ++k) {
            int j = nbr[i*KNB + k];
            float w = wmat[i*KNB + k];
            float er0 = xyz1[3*j]  - cr0, er1 = xyz1[3*j+1] - cr1, er2 = xyz1[3*j+2] - cr2;
            float ed0 = recon[3*j] - cd0, ed1 = recon[3*j+1] - cd1, ed2 = recon[3*j+2] - cd2;
            float r0 = ed0 - (R[0][0]*er0 + R[0][1]*er1 + R[0][2]*er2);
            float r1 = ed1 - (R[1][0]*er0 + R[1][1]*er1 + R[1][2]*er2);
            float r2 = ed2 - (R[2][0]*er0 + R[2][1]*er1 + R[2][2]*er2);
            pv += (double)(w * (r0*r0 + r1*r1 + r2*r2));
            float g0 = gscale * w * r0;
            float g1 = gscale * w * r1;
            float g2 = gscale * w * r2;
            atomicAdd(&gv[3*j+0], g0);
            atomicAdd(&gv[3*j+1], g1);
            atomicAdd(&gv[3*j+2], g2);
            own0 += g0; own1 += g1; own2 += g2;
        }
        if (num > 0) {
            atomicAdd(&gv[3*i+0], -own0);
            atomicAdd(&gv[3*i+1], -own1);
            atomicAdd(&gv[3*i+2], -own2);
        }
    }
#pragma unroll
    for (int m = 32; m; m >>= 1) pv += __shfl_xor(pv, m);
    if (threadIdx.x == 0)
        atomicAdd(reinterpret_cast<double*>(ws + OFF_E), pv);
}

// ---------------- backward ----------------

// grid 1024, block 256: g_z2[j] = (h2[j]>0) * dot(W3[j,:], g_v)
__global__ void k_gh2(const float* __restrict__ W3, float* __restrict__ ws) {
    int j = blockIdx.x;
    float h2v = ws[OFF_H2 + j];
    if (h2v <= 0.f) {
        if (threadIdx.x == 0) ws[OFF_GZ2 + j] = 0.f;
        return;
    }
    const float4* w3r = reinterpret_cast<const float4*>(W3 + (size_t)j * M3);
    const float4* gv4 = reinterpret_cast<const float4*>(ws + OFF_GV);
    float acc = 0.f;
    for (int it = threadIdx.x; it < M3 / 4; it += 256) {
        float4 a = w3r[it], g = gv4[it];
        acc += a.x*g.x + a.y*g.y + a.z*g.z + a.w*g.w;
    }
    for (int m = 32; m; m >>= 1) acc += __shfl_xor(acc, m);
    __shared__ float wsum[4];
    if ((threadIdx.x & 63) == 0) wsum[threadIdx.x >> 6] = acc;
    __syncthreads();
    if (threadIdx.x == 0) ws[OFF_GZ2 + j] = wsum[0] + wsum[1] + wsum[2] + wsum[3];
}

// grid 128, block 256 (wave per row): g_z1[i] = (h1[i]>0) * dot(W2[i,:], g_z2)
__global__ void k_gh1(const float* __restrict__ W2, float* __restrict__ ws) {
    int wv = threadIdx.x >> 6, ln = threadIdx.x & 63;
    int i = blockIdx.x * 4 + wv;  // < 512
    const float* gz2 = ws + OFF_GZ2;
    float acc = 0.f;
#pragma unroll
    for (int it = 0; it < H2 / 64; ++it) {
        int jj = ln + it * 64;
        acc += W2[(size_t)i * H2 + jj] * gz2[jj];
    }
    for (int m = 32; m; m >>= 1) acc += __shfl_xor(acc, m);
    if (ln == 0) ws[OFF_GZ1 + i] = (ws[OFF_H1 + i] > 0.f) ? acc : 0.f;
}

// grid 64, block 256 (wave per row): out[1+d] = dot(W1[d,:], g_z1); out[0] = -E/N
__global__ void k_gcode(const float* __restrict__ W1, float* __restrict__ ws,
                        float* __restrict__ out) {
    int wv = threadIdx.x >> 6, ln = threadIdx.x & 63;
    int d = blockIdx.x * 4 + wv;  // < 256
    const float* gz1 = ws + OFF_GZ1;
    float acc = 0.f;
#pragma unroll
    for (int it = 0; it < H1 / 64; ++it) {
        int ii = ln + it * 64;
        acc += W1[(size_t)d * H1 + ii] * gz1[ii];
    }
    for (int m = 32; m; m >>= 1) acc += __shfl_xor(acc, m);
    if (ln == 0) out[1 + d] = acc;
    if (blockIdx.x == 0 && threadIdx.x == 0) {
        double E = *reinterpret_cast<const double*>(ws + OFF_E);
        out[0] = (float)(-(E / (double)N_V));
    }
}

extern "C" void kernel_launch(void* const* d_in, const int* in_sizes, int n_in,
                              void* d_out, int out_size, void* d_ws, size_t ws_size,
                              hipStream_t stream) {
    const float* code = (const float*)d_in[0];
    const float* xyz1 = (const float*)d_in[1];
    const float* wmat = (const float*)d_in[2];
    const float* W1   = (const float*)d_in[3];
    const float* b1   = (const float*)d_in[4];
    const float* W2   = (const float*)d_in[5];
    const float* b2   = (const float*)d_in[6];
    const float* W3   = (const float*)d_in[7];
    const float* b3   = (const float*)d_in[8];
    const int*   nbr  = (const int*)d_in[9];
    const int*   nnum = (const int*)d_in[10];
    float* out = (float*)d_out;
    float* ws  = (float*)d_ws;

    k_mlp  <<<32,          256, 0, stream>>>(code, W1, b1, W2, b2, b3, ws);
    k_l3v  <<<dim3(59, 8), 256, 0, stream>>>(W3, ws);
    k_arap <<<313,          64, 0, stream>>>(xyz1, wmat, nbr, nnum, ws);
    k_gh2  <<<1024,        256, 0, stream>>>(W3, ws);
    k_gh1  <<<128,         256, 0, stream>>>(W2, ws);
    k_gcode<<<64,          256, 0, stream>>>(W1, ws, out);
}

// Round 5
// 120.763 us; speedup vs baseline: 1.1854x; 1.1854x over previous
//
#include <hip/hip_runtime.h>
#include <hip/hip_bf16.h>

#define N_V   20000
#define KNB   16
#define DCODE 256
#define H1    512
#define H2    1024
#define M3    60000   // N_V * 3

// ws layout (float offsets)
#define OFF_L2P   0          // 8*1024 -> 8192
#define OFF_VPART 8192       // 8*60000 -> 488192
#define OFF_V     488192     // 60000 -> 548192
#define OFF_GV    548192     // 60000 -> 608192
#define OFF_GZ2   608192     // 1024 -> 609216
#define OFF_GZ1   609216     // 512  -> 609728
#define OFF_H1    609728     // 512  -> 610240
#define OFF_H2    610240     // 1024 -> 611264
#define OFF_HC    611264     // 1024 -> 612288
#define OFF_LIST  612288     // 1024 ints -> 613312
#define OFF_CNT   613312     // 2 ints -> 613314
#define OFF_E     613316     // double (byte 2453264 % 8 == 0)

// ---------------- layers 1+2 fused ----------------
// grid (4, 8), block 256. Block (bx,dz): h1 chunk [dz*64, dz*64+64) computed
// locally (x4 redundancy), then z2 partial for cols bx*256.. over that d-chunk.
// Also zeros gv and E.
__global__ void k_mlp12(const float* __restrict__ code, const float* __restrict__ W1,
                        const float* __restrict__ b1, const float* __restrict__ W2,
                        float* __restrict__ ws) {
    __shared__ float red[4][64];
    __shared__ float h1s[64];
    int t = threadIdx.x;
    int bx = blockIdx.x, dz = blockIdx.y;
    int d0 = dz * 64;

    // h1 chunk: col c = d0 + (t&63), partial over rows g*64..g*64+63
    int ln = t & 63, g = t >> 6;
    {
        float acc = 0.f;
        int r0 = g * 64;
#pragma unroll 8
        for (int rr = 0; rr < 64; ++rr)
            acc += code[r0 + rr] * W1[(size_t)(r0 + rr) * H1 + d0 + ln];
        red[g][ln] = acc;
    }
    __syncthreads();
    if (g == 0) {
        float h = fmaxf(red[0][ln] + red[1][ln] + red[2][ln] + red[3][ln] + b1[d0 + ln], 0.f);
        h1s[ln] = h;
        if (bx == 0) ws[OFF_H1 + d0 + ln] = h;
    }
    __syncthreads();

    // z2 partial: col m = bx*256 + t over d-chunk [d0, d0+64)
    int m = bx * 256 + t;
    float acc = 0.f;
#pragma unroll 8
    for (int dd = 0; dd < 64; ++dd)
        acc += h1s[dd] * W2[(size_t)(d0 + dd) * H2 + m];
    ws[OFF_L2P + dz * H2 + m] = acc;

    // zero gv and E (32 blocks x 256 = 8192 threads)
    int gid = (dz * 4 + bx) * 256 + t;
    for (int idx = gid; idx < M3; idx += 8192) ws[OFF_GV + idx] = 0.f;
    if (gid == 0) { ws[OFF_E] = 0.f; ws[OFF_E + 1] = 0.f; }
}

// 1 block, 256 threads: h2 = relu(b2 + sum partials), compact live rows, zero gz2
__global__ void k_compact(const float* __restrict__ b2, float* __restrict__ ws) {
    __shared__ int scan[256];
    int t = threadIdx.x;
    float h[4]; int c = 0;
#pragma unroll
    for (int q = 0; q < 4; ++q) {
        int j = t * 4 + q;
        float s = b2[j];
#pragma unroll
        for (int p = 0; p < 8; ++p) s += ws[OFF_L2P + p * H2 + j];
        float hv = fmaxf(s, 0.f);
        ws[OFF_H2 + j] = hv;
        ws[OFF_GZ2 + j] = 0.f;
        h[q] = hv;
        c += (hv > 0.f) ? 1 : 0;
    }
    scan[t] = c;
    __syncthreads();
    for (int off = 1; off < 256; off <<= 1) {
        int x = (t >= off) ? scan[t - off] : 0;
        __syncthreads();
        scan[t] += x;
        __syncthreads();
    }
    int base = scan[t] - c;
    int* list = reinterpret_cast<int*>(&ws[OFF_LIST]);
#pragma unroll
    for (int q = 0; q < 4; ++q) {
        if (h[q] > 0.f) {
            list[base] = t * 4 + q;
            ws[OFF_HC + base] = h[q];
            ++base;
        }
    }
    if (t == 255) *reinterpret_cast<int*>(&ws[OFF_CNT]) = scan[255];
}

// grid (59, 8), block 256: partial v over compacted-row chunk, 8-row unroll
__global__ void k_l3p(const float* __restrict__ W3, float* __restrict__ ws) {
    __shared__ int   rlist[128];
    __shared__ float rh[128];
    int jz = blockIdx.y;
    int cnt = *reinterpret_cast<const int*>(&ws[OFF_CNT]);
    int per = (cnt + 7) >> 3;
    int s0 = jz * per;
    int s1 = s0 + per; if (s1 > cnt) s1 = cnt;
    int n = s1 - s0;
    int t = threadIdx.x;
    if (t < 128 && t < n) {
        rlist[t] = reinterpret_cast<const int*>(&ws[OFF_LIST])[s0 + t];
        rh[t]    = ws[OFF_HC + s0 + t];
    }
    __syncthreads();
    int m4 = blockIdx.x * 1024 + t * 4;
    if (m4 >= M3) return;
    float ax = 0.f, ay = 0.f, az = 0.f, aw = 0.f;
    int ii = 0;
    for (; ii + 7 < n; ii += 8) {
        float4 wv[8];
#pragma unroll
        for (int u = 0; u < 8; ++u)
            wv[u] = *reinterpret_cast<const float4*>(&W3[(size_t)rlist[ii + u] * M3 + m4]);
#pragma unroll
        for (int u = 0; u < 8; ++u) {
            float h = rh[ii + u];
            ax += h * wv[u].x; ay += h * wv[u].y; az += h * wv[u].z; aw += h * wv[u].w;
        }
    }
    for (; ii < n; ++ii) {
        float h = rh[ii];
        float4 wv = *reinterpret_cast<const float4*>(&W3[(size_t)rlist[ii] * M3 + m4]);
        ax += h * wv.x; ay += h * wv.y; az += h * wv.z; aw += h * wv.w;
    }
    *reinterpret_cast<float4*>(&ws[OFF_VPART + jz * M3 + m4]) =
        make_float4(ax, ay, az, aw);
}

// grid 59, block 256: v = b3 + sum of 8 partials
__global__ void k_vred(const float* __restrict__ b3, float* __restrict__ ws) {
    int i4 = blockIdx.x * 256 + threadIdx.x;
    if (i4 < M3 / 4) {
        int m = i4 * 4;
        float4 a = *reinterpret_cast<const float4*>(&b3[m]);
#pragma unroll
        for (int jz = 0; jz < 8; ++jz) {
            float4 p = *reinterpret_cast<const float4*>(&ws[OFF_VPART + jz * M3 + m]);
            a.x += p.x; a.y += p.y; a.z += p.z; a.w += p.w;
        }
        *reinterpret_cast<float4*>(&ws[OFF_V + m]) = a;
    }
}

// ---------------- ARAP fused fp32, single gather pass ----------------

__device__ inline void jrotf(float a[3][3], float v[3][3], int p, int q) {
    float apq = a[p][q];
    if (fabsf(apq) < 1e-30f) return;
    float theta = (a[q][q] - a[p][p]) / (2.0f * apq);
    float t;
    if (fabsf(theta) > 1e18f) t = 0.5f / theta;
    else t = copysignf(1.0f, theta) / (fabsf(theta) + sqrtf(theta * theta + 1.0f));
    float c = 1.0f / sqrtf(t * t + 1.0f);
    float s = t * c;
    float app = a[p][p], aqq = a[q][q];
    a[p][p] = app - t * apq;
    a[q][q] = aqq + t * apq;
    a[p][q] = 0.0f; a[q][p] = 0.0f;
    int r = 3 - p - q;
    float arp = a[r][p], arq = a[r][q];
    a[r][p] = c * arp - s * arq; a[p][r] = a[r][p];
    a[r][q] = s * arp + c * arq; a[q][r] = a[r][q];
#pragma unroll
    for (int k2 = 0; k2 < 3; ++k2) {
        float vkp = v[k2][p], vkq = v[k2][q];
        v[k2][p] = c * vkp - s * vkq;
        v[k2][q] = s * vkp + c * vkq;
    }
}

__device__ void compute_Rf(const float S[3][3], float R[3][3]) {
    float A[3][3], V[3][3];
#pragma unroll
    for (int a = 0; a < 3; ++a)
#pragma unroll
        for (int b = 0; b < 3; ++b) {
            float s = 0.0f;
#pragma unroll
            for (int c = 0; c < 3; ++c) s += S[c][a] * S[c][b];
            A[a][b] = s;
            V[a][b] = (a == b) ? 1.0f : 0.0f;
        }
    for (int sweep = 0; sweep < 15; ++sweep) {
        float off = A[0][1]*A[0][1] + A[0][2]*A[0][2] + A[1][2]*A[1][2];
        float dg  = A[0][0]*A[0][0] + A[1][1]*A[1][1] + A[2][2]*A[2][2];
        if (off <= 1e-12f * (dg + 1e-30f)) break;
        jrotf(A, V, 0, 1); jrotf(A, V, 0, 2); jrotf(A, V, 1, 2);
    }
    int id[3] = {0, 1, 2};
    if (A[id[0]][id[0]] < A[id[1]][id[1]]) { int t = id[0]; id[0] = id[1]; id[1] = t; }
    if (A[id[0]][id[0]] < A[id[2]][id[2]]) { int t = id[0]; id[0] = id[2]; id[2] = t; }
    if (A[id[1]][id[1]] < A[id[2]][id[2]]) { int t = id[1]; id[1] = id[2]; id[2] = t; }
    float v0[3], v1[3], v2[3];
#pragma unroll
    for (int r = 0; r < 3; ++r) {
        v0[r] = V[r][id[0]]; v1[r] = V[r][id[1]]; v2[r] = V[r][id[2]];
    }
    float u0[3], u1[3], u2[3];
#pragma unroll
    for (int a = 0; a < 3; ++a)
        u0[a] = S[a][0]*v0[0] + S[a][1]*v0[1] + S[a][2]*v0[2];
    float n0 = sqrtf(u0[0]*u0[0] + u0[1]*u0[1] + u0[2]*u0[2]);
    if (!(n0 > 1e-20f)) {
#pragma unroll
        for (int a = 0; a < 3; ++a)
#pragma unroll
            for (int c = 0; c < 3; ++c) R[a][c] = (a == c) ? 1.0f : 0.0f;
        return;
    }
#pragma unroll
    for (int a = 0; a < 3; ++a) u0[a] /= n0;
    float t1[3];
#pragma unroll
    for (int a = 0; a < 3; ++a)
        t1[a] = S[a][0]*v1[0] + S[a][1]*v1[1] + S[a][2]*v1[2];
    float dp = u0[0]*t1[0] + u0[1]*t1[1] + u0[2]*t1[2];
#pragma unroll
    for (int a = 0; a < 3; ++a) t1[a] -= dp * u0[a];
    float n1 = sqrtf(t1[0]*t1[0] + t1[1]*t1[1] + t1[2]*t1[2]);
    if (n1 > 1e-5f * n0) {
#pragma unroll
        for (int a = 0; a < 3; ++a) u1[a] = t1[a] / n1;
    } else {
        int m = (fabsf(u0[0]) <= fabsf(u0[1]) && fabsf(u0[0]) <= fabsf(u0[2])) ? 0
              : (fabsf(u0[1]) <= fabsf(u0[2]) ? 1 : 2);
        float e[3] = {0.0f, 0.0f, 0.0f}; e[m] = 1.0f;
        float cx[3] = { u0[1]*e[2] - u0[2]*e[1],
                        u0[2]*e[0] - u0[0]*e[2],
                        u0[0]*e[1] - u0[1]*e[0] };
        float nn = sqrtf(cx[0]*cx[0] + cx[1]*cx[1] + cx[2]*cx[2]);
#pragma unroll
        for (int a = 0; a < 3; ++a) u1[a] = cx[a] / nn;
    }
    u2[0] = u0[1]*u1[2] - u0[2]*u1[1];
    u2[1] = u0[2]*u1[0] - u0[0]*u1[2];
    u2[2] = u0[0]*u1[1] - u0[1]*u1[0];
    float d = v0[0]*(v1[1]*v2[2] - v1[2]*v2[1])
            - v0[1]*(v1[0]*v2[2] - v1[2]*v2[0])
            + v0[2]*(v1[0]*v2[1] - v1[1]*v2[0]);
#pragma unroll
    for (int a = 0; a < 3; ++a)
#pragma unroll
        for (int c = 0; c < 3; ++c)
            R[a][c] = v0[a]*u0[c] + v1[a]*u1[c] + d * (v2[a]*u2[c]);
}

// grid 79, block 256: single gather pass; er/ed stashed in registers
__global__ void k_arap(const float* __restrict__ xyz1, const float* __restrict__ wmat,
                       const int* __restrict__ nbr, const int* __restrict__ nnum,
                       float* __restrict__ ws) {
    const float* recon = ws + OFF_V;
    float* gv = ws + OFF_GV;
    int i = blockIdx.x * 256 + threadIdx.x;
    double pv = 0.0;
    if (i < N_V) {
        int num = nnum[i]; if (num > KNB) num = KNB;
        float cr0 = xyz1[3*i], cr1 = xyz1[3*i+1], cr2 = xyz1[3*i+2];
        float cd0 = recon[3*i], cd1 = recon[3*i+1], cd2 = recon[3*i+2];
        float er[KNB][3], ed[KNB][3], wk[KNB];
        int   jn[KNB];
        float S[3][3] = {{0,0,0},{0,0,0},{0,0,0}};
#pragma unroll
        for (int k = 0; k < KNB; ++k) {
            bool live = (k < num);
            int j = live ? nbr[i*KNB + k] : i;
            float w = live ? wmat[i*KNB + k] : 0.f;
            jn[k] = j; wk[k] = w;
            float e0 = xyz1[3*j]   - cr0, e1 = xyz1[3*j+1] - cr1, e2 = xyz1[3*j+2] - cr2;
            float f0 = recon[3*j]  - cd0, f1 = recon[3*j+1] - cd1, f2 = recon[3*j+2] - cd2;
            er[k][0] = e0; er[k][1] = e1; er[k][2] = e2;
            ed[k][0] = f0; ed[k][1] = f1; ed[k][2] = f2;
            S[0][0] += w*e0*f0; S[0][1] += w*e0*f1; S[0][2] += w*e0*f2;
            S[1][0] += w*e1*f0; S[1][1] += w*e1*f1; S[1][2] += w*e1*f2;
            S[2][0] += w*e2*f0; S[2][1] += w*e2*f1; S[2][2] += w*e2*f2;
        }
        float R[3][3];
        compute_Rf(S, R);
        const float gscale = 2.0f / (float)N_V;
        float own0 = 0.f, own1 = 0.f, own2 = 0.f;
#pragma unroll
        for (int k = 0; k < KNB; ++k) {
            if (k < num) {
                float w = wk[k];
                float r0 = ed[k][0] - (R[0][0]*er[k][0] + R[0][1]*er[k][1] + R[0][2]*er[k][2]);
                float r1 = ed[k][1] - (R[1][0]*er[k][0] + R[1][1]*er[k][1] + R[1][2]*er[k][2]);
                float r2 = ed[k][2] - (R[2][0]*er[k][0] + R[2][1]*er[k][1] + R[2][2]*er[k][2]);
                pv += (double)(w * (r0*r0 + r1*r1 + r2*r2));
                float g0 = gscale * w * r0;
                float g1 = gscale * w * r1;
                float g2 = gscale * w * r2;
                int j = jn[k];
                atomicAdd(&gv[3*j+0], g0);
                atomicAdd(&gv[3*j+1], g1);
                atomicAdd(&gv[3*j+2], g2);
                own0 += g0; own1 += g1; own2 += g2;
            }
        }
        if (num > 0) {
            atomicAdd(&gv[3*i+0], -own0);
            atomicAdd(&gv[3*i+1], -own1);
            atomicAdd(&gv[3*i+2], -own2);
        }
    }
#pragma unroll
    for (int m = 32; m; m >>= 1) pv += __shfl_xor(pv, m);
    __shared__ double wred[4];
    if ((threadIdx.x & 63) == 0) wred[threadIdx.x >> 6] = pv;
    __syncthreads();
    if (threadIdx.x == 0)
        atomicAdd(reinterpret_cast<double*>(ws + OFF_E),
                  wred[0] + wred[1] + wred[2] + wred[3]);
}

// ---------------- backward ----------------

// grid 512, block 256: two list rows per block; gv read once, used twice
__global__ void k_gh2(const float* __restrict__ W3, float* __restrict__ ws) {
    int b = blockIdx.x;
    int cnt = *reinterpret_cast<const int*>(&ws[OFF_CNT]);
    if (2 * b >= cnt) return;
    const int* list = reinterpret_cast<const int*>(&ws[OFF_LIST]);
    int j0 = list[2 * b];
    bool has1 = (2 * b + 1 < cnt);
    int j1 = has1 ? list[2 * b + 1] : j0;
    const float4* w3r0 = reinterpret_cast<const float4*>(W3 + (size_t)j0 * M3);
    const float4* w3r1 = reinterpret_cast<const float4*>(W3 + (size_t)j1 * M3);
    const float4* gv4  = reinterpret_cast<const float4*>(ws + OFF_GV);
    float acc0 = 0.f, acc1 = 0.f;
    for (int it = threadIdx.x; it < M3 / 4; it += 256) {
        float4 g = gv4[it];
        float4 a = w3r0[it];
        float4 c = w3r1[it];
        acc0 += a.x*g.x + a.y*g.y + a.z*g.z + a.w*g.w;
        acc1 += c.x*g.x + c.y*g.y + c.z*g.z + c.w*g.w;
    }
    for (int m = 32; m; m >>= 1) {
        acc0 += __shfl_xor(acc0, m);
        acc1 += __shfl_xor(acc1, m);
    }
    __shared__ float wsum[4][2];
    if ((threadIdx.x & 63) == 0) {
        wsum[threadIdx.x >> 6][0] = acc0;
        wsum[threadIdx.x >> 6][1] = acc1;
    }
    __syncthreads();
    if (threadIdx.x == 0) {
        ws[OFF_GZ2 + j0] = wsum[0][0] + wsum[1][0] + wsum[2][0] + wsum[3][0];
        if (has1)
            ws[OFF_GZ2 + j1] = wsum[0][1] + wsum[1][1] + wsum[2][1] + wsum[3][1];
    }
}

// grid 128, block 256 (wave per row): g_z1[i] = (h1[i]>0) * dot(W2[i,:], g_z2)
__global__ void k_gh1(const float* __restrict__ W2, float* __restrict__ ws) {
    int wv = threadIdx.x >> 6, ln = threadIdx.x & 63;
    int i = blockIdx.x * 4 + wv;  // < 512
    const float* gz2 = ws + OFF_GZ2;
    float acc = 0.f;
#pragma unroll
    for (int it = 0; it < H2 / 64; ++it) {
        int jj = ln + it * 64;
        acc += W2[(size_t)i * H2 + jj] * gz2[jj];
    }
    for (int m = 32; m; m >>= 1) acc += __shfl_xor(acc, m);
    if (ln == 0) ws[OFF_GZ1 + i] = (ws[OFF_H1 + i] > 0.f) ? acc : 0.f;
}

// grid 64, block 256 (wave per row): out[1+d] = dot(W1[d,:], g_z1); out[0] = -E/N
__global__ void k_gcode(const float* __restrict__ W1, float* __restrict__ ws,
                        float* __restrict__ out) {
    int wv = threadIdx.x >> 6, ln = threadIdx.x & 63;
    int d = blockIdx.x * 4 + wv;  // < 256
    const float* gz1 = ws + OFF_GZ1;
    float acc = 0.f;
#pragma unroll
    for (int it = 0; it < H1 / 64; ++it) {
        int ii = ln + it * 64;
        acc += W1[(size_t)d * H1 + ii] * gz1[ii];
    }
    for (int m = 32; m; m >>= 1) acc += __shfl_xor(acc, m);
    if (ln == 0) out[1 + d] = acc;
    if (blockIdx.x == 0 && threadIdx.x == 0) {
        double E = *reinterpret_cast<const double*>(ws + OFF_E);
        out[0] = (float)(-(E / (double)N_V));
    }
}

extern "C" void kernel_launch(void* const* d_in, const int* in_sizes, int n_in,
                              void* d_out, int out_size, void* d_ws, size_t ws_size,
                              hipStream_t stream) {
    const float* code = (const float*)d_in[0];
    const float* xyz1 = (const float*)d_in[1];
    const float* wmat = (const float*)d_in[2];
    const float* W1   = (const float*)d_in[3];
    const float* b1   = (const float*)d_in[4];
    const float* W2   = (const float*)d_in[5];
    const float* b2   = (const float*)d_in[6];
    const float* W3   = (const float*)d_in[7];
    const float* b3   = (const float*)d_in[8];
    const int*   nbr  = (const int*)d_in[9];
    const int*   nnum = (const int*)d_in[10];
    float* out = (float*)d_out;
    float* ws  = (float*)d_ws;

    k_mlp12  <<<dim3(4, 8),  256, 0, stream>>>(code, W1, b1, W2, ws);
    k_compact<<<1,           256, 0, stream>>>(b2, ws);
    k_l3p    <<<dim3(59, 8), 256, 0, stream>>>(W3, ws);
    k_vred   <<<59,          256, 0, stream>>>(b3, ws);
    k_arap   <<<79,          256, 0, stream>>>(xyz1, wmat, nbr, nnum, ws);
    k_gh2    <<<512,         256, 0, stream>>>(W3, ws);
    k_gh1    <<<128,         256, 0, stream>>>(W2, ws);
    k_gcode  <<<64,          256, 0, stream>>>(W1, ws, out);
}